// Round 15
// baseline (47.597 us; speedup 1.0000x reference)
//
#include <hip/hip_runtime.h>
#include <math.h>

// MAM "FullyConnected": C[n,m] = max_k(x[n,k]*w[m,k]) + min_k(...) + bias[m]
// plus argmax/argmin (first occurrence). N=1024, M=512, K=512, f32.
// d_out (read back as f32): C | argmax | argmin, each N*M.
//
// Round 15: barrier-free main loop. All prior rounds convoyed on per-BK
// __syncthreads (wall ~2x VALU-busy at every occupancy). Now: w[16][516]
// (full K, 33KB, 2-way-aliased only) staged ONCE, one barrier, then each
// thread owns ONE cell and free-runs K=512 in 32 tournament groups --
// x from global/L1, w from LDS, no barriers, no k-split, no merge.
// 2048 blocks x 4 waves, 4 blocks/CU (LDS-bound) = 16 independent waves/CU.

constexpr int NTOT = 1024;
constexpr int MTOT = 512;
constexpr int KTOT = 512;
constexpr int BN = 16;
constexpr int BM = 16;
constexpr int G  = 16;        // tournament group size
constexpr int LDSPW = 516;    // 512+4: rows 16B-aligned, 4c mod 32 -> 2-way only

__device__ __forceinline__ float max3f(float a, float b, float c) {
  float d; asm("v_max3_f32 %0, %1, %2, %3" : "=v"(d) : "v"(a), "v"(b), "v"(c)); return d;
}
__device__ __forceinline__ float min3f(float a, float b, float c) {
  float d; asm("v_min3_f32 %0, %1, %2, %3" : "=v"(d) : "v"(a), "v"(b), "v"(c)); return d;
}
__device__ __forceinline__ float fmul0(float a, float b) {  // a*b on the 2-cy FMA pipe
  float d; asm("v_fma_f32 %0, %1, %2, 0" : "=v"(d) : "v"(a), "v"(b)); return d;
}
__device__ __forceinline__ float4 f4mul(float4 a, float4 b) {
  return make_float4(fmul0(a.x, b.x), fmul0(a.y, b.y), fmul0(a.z, b.z), fmul0(a.w, b.w));
}

__device__ __forceinline__ void tree16(const float4& q0, const float4& q1,
                                       const float4& q2, const float4& q3,
                                       float& M, float& m) {
  M = fmaxf(max3f(max3f(q0.x, q0.y, q0.z), max3f(q0.w, q1.x, q1.y),
                  max3f(q1.z, q1.w, q2.x)),
            max3f(max3f(q2.y, q2.z, q2.w), q3.x, max3f(q3.y, q3.z, q3.w)));
  m = fminf(min3f(min3f(q0.x, q0.y, q0.z), min3f(q0.w, q1.x, q1.y),
                  min3f(q1.z, q1.w, q2.x)),
            min3f(min3f(q2.y, q2.z, q2.w), q3.x, min3f(q3.y, q3.z, q3.w)));
}

// first k in [base, base+16) with x[k]*w[k] == tgt (descending selects ->
// first occurrence wins; +-0 compare-equal so fma(+0) targets match mul).
__device__ __forceinline__ int find_first_eq(const float* __restrict__ xr,
                                             const float* __restrict__ wr,
                                             float tgt, int base) {
  const float4 a0 = *(const float4*)(xr + 0),  a1 = *(const float4*)(xr + 4);
  const float4 a2 = *(const float4*)(xr + 8),  a3 = *(const float4*)(xr + 12);
  const float4 b0 = *(const float4*)(wr + 0),  b1 = *(const float4*)(wr + 4);
  const float4 b2 = *(const float4*)(wr + 8),  b3 = *(const float4*)(wr + 12);
  int idx = base;
  idx = (a3.w * b3.w == tgt) ? base + 15 : idx;
  idx = (a3.z * b3.z == tgt) ? base + 14 : idx;
  idx = (a3.y * b3.y == tgt) ? base + 13 : idx;
  idx = (a3.x * b3.x == tgt) ? base + 12 : idx;
  idx = (a2.w * b2.w == tgt) ? base + 11 : idx;
  idx = (a2.z * b2.z == tgt) ? base + 10 : idx;
  idx = (a2.y * b2.y == tgt) ? base +  9 : idx;
  idx = (a2.x * b2.x == tgt) ? base +  8 : idx;
  idx = (a1.w * b1.w == tgt) ? base +  7 : idx;
  idx = (a1.z * b1.z == tgt) ? base +  6 : idx;
  idx = (a1.y * b1.y == tgt) ? base +  5 : idx;
  idx = (a1.x * b1.x == tgt) ? base +  4 : idx;
  idx = (a0.w * b0.w == tgt) ? base +  3 : idx;
  idx = (a0.z * b0.z == tgt) ? base +  2 : idx;
  idx = (a0.y * b0.y == tgt) ? base +  1 : idx;
  idx = (a0.x * b0.x == tgt) ? base +  0 : idx;
  return idx;
}

__global__ __launch_bounds__(256, 4) void mam_kernel(
    const float* __restrict__ X,   // [NTOT][KTOT]
    const float* __restrict__ W,   // [MTOT][KTOT]
    const float* __restrict__ B,   // [MTOT]
    float* __restrict__ out)
{
  __shared__ float sw[BM][LDSPW];   // 33 KB: w tile for the ENTIRE K

  const int th = threadIdx.x;          // 0..255
  const int r  = th >> 4;              // 0..15 row within tile
  const int c  = th & 15;              // 0..15 col within tile
  const int n0 = blockIdx.y * BN;
  const int m0 = blockIdx.x * BM;
  const int n  = n0 + r;
  const int m  = m0 + c;

  // ---- stage w[16][512] once: 2048 float4, 256 threads -> 8 each ----
  #pragma unroll
  for (int j = 0; j < 8; ++j) {
    const int id  = th + 256 * j;      // 0..2047
    const int row = id >> 7;           // 0..15
    const int f   = id & 127;          // float4 slot within 512-float row
    *reinterpret_cast<float4*>(&sw[row][f * 4]) =
        *reinterpret_cast<const float4*>(&W[(m0 + row) * KTOT + f * 4]);
  }
  __syncthreads();   // the ONLY barrier

  // ---- barrier-free main loop: full K per thread, one cell ----
  const float* Xr = &X[n * KTOT];

  float vmax = -INFINITY, vmin = INFINITY;
  int   gx = 0, gn = 0;

  #pragma unroll 4
  for (int g = 0; g < KTOT / G; ++g) {  // 32 groups of 16 k
    const int off = g * G;
    // x from global (L1-resident: 16 rows x 2KB = 32KB window; 16 lanes
    // with same r share the address -> one 16B request each)
    const float4 x0 = *reinterpret_cast<const float4*>(Xr + off + 0);
    const float4 x1 = *reinterpret_cast<const float4*>(Xr + off + 4);
    const float4 x2 = *reinterpret_cast<const float4*>(Xr + off + 8);
    const float4 x3 = *reinterpret_cast<const float4*>(Xr + off + 12);
    // w from LDS (4c mod 32 bank layout: 2-way aliasing only, free)
    const float4* wp = reinterpret_cast<const float4*>(&sw[c][off]);
    const float4 w0 = wp[0], w1 = wp[1], w2 = wp[2], w3 = wp[3];

    const float4 q0 = f4mul(x0, w0), q1 = f4mul(x1, w1);
    const float4 q2 = f4mul(x2, w2), q3 = f4mul(x3, w3);
    float M, mn;
    tree16(q0, q1, q2, q3, M, mn);
    const bool u = M > vmax;            // strict: first group wins
    vmax = u ? M : vmax;  gx = u ? off : gx;
    const bool v = mn < vmin;
    vmin = v ? mn : vmin;  gn = v ? off : gn;
  }

  // ---- windowed index recovery (L1/L2 hits) ----
  const float* Wr = &W[m * KTOT];
  const int imax = find_first_eq(Xr + gx, Wr + gx, vmax, gx);
  const int imin = find_first_eq(Xr + gn, Wr + gn, vmin, gn);

  // ---- output ----
  float* Cout = out;
  float* AM   = out + NTOT * MTOT;
  float* AN   = AM + NTOT * MTOT;
  const int o = n * MTOT + m;
  Cout[o] = vmax + vmin + B[m];
  AM[o]   = (float)imax;
  AN[o]   = (float)imin;
}

extern "C" void kernel_launch(void* const* d_in, const int* in_sizes, int n_in,
                              void* d_out, int out_size, void* d_ws, size_t ws_size,
                              hipStream_t stream) {
  const float* X = (const float*)d_in[0];   // [8,128,512] -> [1024][512]
  const float* W = (const float*)d_in[1];   // [512][512]
  const float* B = (const float*)d_in[2];   // [512]
  float* out = (float*)d_out;

  dim3 grid(MTOT / BM, NTOT / BN);          // (32, 64) = 2048 blocks, 256 thr
  mam_kernel<<<grid, dim3(256), 0, stream>>>(X, W, B, out);
}